// Round 5
// baseline (800.569 us; speedup 1.0000x reference)
//
#include <hip/hip_runtime.h>
#include <stdint.h>

#define N_ATOMS 8192
#define EMBED   32
#define DEPTHN  10

typedef short bf16x8 __attribute__((ext_vector_type(8)));
typedef float f32x4  __attribute__((ext_vector_type(4)));

__device__ __forceinline__ unsigned short f2bf(float f){
    unsigned u = __builtin_bit_cast(unsigned, f);
    u = u + 0x7FFFu + ((u >> 16) & 1u);
    return (unsigned short)(u >> 16);
}

// ---------------------------------------------------------------------------
// k_preA (fallback path only; R10-proven form): one row per block. Row-major
// mask64 writes, LDS staged. u32 word g of row i covers cols 32g..32g+31.
// ---------------------------------------------------------------------------
__global__ __launch_bounds__(256) void k_preA(const int* __restrict__ A,
                                              unsigned long long* __restrict__ mask,
                                              int row0)
{
    const int i = row0 + blockIdx.x;
    const int t = threadIdx.x, w = t >> 6, l = t & 63;
    const int* row = A + (size_t)i * N_ATOMS;
    __shared__ unsigned long long lm[128];
    #pragma unroll
    for (int k = 0; k < 32; ++k){
        int j = k*256 + t;
        unsigned long long m = __ballot(row[j] != 0);
        if (l == 0) lm[k*4 + w] = m;
    }
    __syncthreads();
    if (t < 128) mask[(size_t)i*128 + t] = lm[t];
}

// ---------------------------------------------------------------------------
// k_pre2 (wsok path): ONE dispatch = setup + preA-direct.
// ORDER MATTERS: setup blocks are 0..3315 so they grab CUs FIRST and run
// UNDER the HBM-bound A-scan (R4 had them last -> serial ~5us tail).
//  blocks 0..3315   : h0 gather, Wc/bc precompute, bond gather
//  blocks 3316+     : mask row -> mP DIRECTLY (packed MFMA order) + deg
//                     via popc. Row swizzle keeps the 16 writers of each
//                     128-B mP line in one XCD/dispatch window.
// ---------------------------------------------------------------------------
__global__ __launch_bounds__(256) void k_pre2(
    const int* __restrict__ A, unsigned* __restrict__ mP,
    float* __restrict__ deg, float* __restrict__ invdeg,
    const int* __restrict__ af, const float* __restrict__ atom_emb,
    const float* __restrict__ msgW, const float* __restrict__ msgb,
    const float* __restrict__ Wih, const float* __restrict__ bih,
    float* __restrict__ hA, unsigned short* __restrict__ hP,
    float* __restrict__ Wc, float* __restrict__ bc,
    const int* __restrict__ bfeat, const float* __restrict__ bondf,
    float* __restrict__ out1)
{
    const int t = threadIdx.x;
    __shared__ unsigned lm[256];
    __shared__ int red[4];
    if (blockIdx.x >= 3316){
        const int blk = blockIdx.x - 3316;
        const int grp = (blk >> 7)*8 + (blk & 7);
        const int n   = (blk >> 3) & 15;
        const int i   = grp*16 + n;
        const int w = t >> 6, l = t & 63;
        const int* row = A + (size_t)i * N_ATOMS;
        #pragma unroll
        for (int k = 0; k < 32; ++k){
            int j = k*256 + t;
            unsigned long long m = __ballot(row[j] != 0);
            if (l == 0){
                lm[(k*4 + w)*2]     = (unsigned)m;
                lm[(k*4 + w)*2 + 1] = (unsigned)(m >> 32);
            }
        }
        __syncthreads();
        // degree: integer popc over the 256 u32 words (order-free, exact)
        int cnt = __popc(lm[t]);
        #pragma unroll
        for (int off = 32; off >= 1; off >>= 1) cnt += __shfl_down(cnt, off, 64);
        if (l == 0) red[w] = cnt;
        __syncthreads();
        if (t == 0){
            int s = red[0] + red[1] + red[2] + red[3];
            deg[i] = (float)s;
            invdeg[i] = 1.f / fmaxf((float)s, 1.f);
        }
        // direct packed-order scatter: mP[grp*4096 + g*16 + n] = rowword g
        mP[(size_t)grp*4096 + t*16 + n] = lm[t];
    } else {
        const int blk = blockIdx.x;
        if (blk < 1024){                       // h0: 8192*32
            int idx = blk*256 + t;
            int i = idx >> 5, e = idx & 31;
            float v = atom_emb[af[i]*EMBED + e];
            hA[idx] = v;
            int g = i >> 5, qd = (i >> 3) & 3, j8 = i & 7;
            hP[(size_t)((g*2 + (e>>4))*64 + qd*16 + (e&15))*8 + j8] = f2bf(v);
        } else if (blk < 1264){                // Wc: 10*96*64, K=256
            int o = (blk-1024)*256 + t;
            int d = o / 6144, r = o % 6144, g = r >> 6, e = r & 63;
            const float* wi = Wih  + (size_t)(d*96 + g)*256;
            const float* mw = msgW + (size_t)d*256*64 + e;
            float acc = 0.f;
            for (int hh = 0; hh < 256; ++hh) acc += wi[hh] * mw[hh*64];
            Wc[o] = acc;
        } else if (blk < 1268){                // bc: 10*96
            int o = (blk-1264)*256 + t;
            if (o < 960){
                int d = o / 96;
                const float* wi = Wih + (size_t)o*256;   // o = d*96+g
                const float* mb = msgb + d*256;
                float acc = 0.f;
                for (int hh = 0; hh < 256; ++hh) acc += wi[hh] * mb[hh];
                bc[o] = acc + bih[o];
            }
        } else {                               // bond embeddings: 16384*32
            int idx = (blk-1268)*256 + t;
            out1[idx] = bondf[bfeat[idx >> 5]*EMBED + (idx & 31)];
        }
    }
}

// ---------------------------------------------------------------------------
// k_prep (fallback path only): FUSED k_pack + k_setup, exactly as R2.
// ---------------------------------------------------------------------------
__global__ __launch_bounds__(256) void k_prep(
    const unsigned* __restrict__ maskRM, unsigned* __restrict__ mP,
    float* __restrict__ deg, float* __restrict__ invdeg,
    const int* __restrict__ af, const float* __restrict__ atom_emb,
    const float* __restrict__ msgW, const float* __restrict__ msgb,
    const float* __restrict__ Wih, const float* __restrict__ bih,
    float* __restrict__ hA, unsigned short* __restrict__ hP,
    float* __restrict__ Wc, float* __restrict__ bc,
    const int* __restrict__ bfeat, const float* __restrict__ bondf,
    float* __restrict__ out1)
{
    const int t = threadIdx.x;
    if (blockIdx.x < 512){
        const int grp = blockIdx.x;
        __shared__ unsigned lm[16*260];
        __shared__ int red[256];
        #pragma unroll
        for (int s = 0; s < 16; ++s)
            lm[s*260 + t] = maskRM[(size_t)grp*4096 + s*256 + t];
        __syncthreads();
        {
            int r = t >> 4, seg = t & 15, cnt = 0;
            #pragma unroll
            for (int k = 0; k < 16; ++k) cnt += __popc(lm[r*260 + seg*16 + k]);
            red[t] = cnt; __syncthreads();
            if (t < 16){
                int s = 0;
                #pragma unroll
                for (int k = 0; k < 16; ++k) s += red[t*16 + k];
                deg[grp*16 + t] = (float)s;
                invdeg[grp*16 + t] = 1.f / fmaxf((float)s, 1.f);
            }
        }
        unsigned* out = mP + (size_t)grp*4096;
        #pragma unroll
        for (int s = 0; s < 16; ++s){
            int W = s*256 + t;
            out[W] = lm[(W & 15)*260 + (W >> 4)];
        }
    } else {
        const int blk = blockIdx.x - 512;
        if (blk < 1024){                       // h0: 8192*32
            int idx = blk*256 + t;
            int i = idx >> 5, e = idx & 31;
            float v = atom_emb[af[i]*EMBED + e];
            hA[idx] = v;
            int g = i >> 5, qd = (i >> 3) & 3, j8 = i & 7;
            hP[(size_t)((g*2 + (e>>4))*64 + qd*16 + (e&15))*8 + j8] = f2bf(v);
        } else if (blk < 1264){                // Wc
            int o = (blk-1024)*256 + t;
            int d = o / 6144, r = o % 6144, g = r >> 6, e = r & 63;
            const float* wi = Wih  + (size_t)(d*96 + g)*256;
            const float* mw = msgW + (size_t)d*256*64 + e;
            float acc = 0.f;
            for (int hh = 0; hh < 256; ++hh) acc += wi[hh] * mw[hh*64];
            Wc[o] = acc;
        } else if (blk < 1268){                // bc
            int o = (blk-1264)*256 + t;
            if (o < 960){
                int d = o / 96;
                const float* wi = Wih + (size_t)o*256;
                const float* mb = msgb + d*256;
                float acc = 0.f;
                for (int hh = 0; hh < 256; ++hh) acc += wi[hh] * mb[hh];
                bc[o] = acc + bih[o];
            }
        } else {                               // bond embeddings
            int idx = (blk-1268)*256 + t;
            out1[idx] = bondf[bfeat[idx >> 5]*EMBED + (idx & 31)];
        }
    }
}

// ---------------------------------------------------------------------------
// k_depth: FUSED k_nei + k_gru. NEW: 128 blocks x 64 atoms (was 256 x 32) ->
// halves phase-A L2 traffic (each block reads full 512 KiB hP once; 64 MiB
// total/depth vs 128) and doubles per-wave ILP (4 row-tiles x 2 halves = 8
// accumulators, 8 MFMAs/kk). q-reduction via TWO SHIFTS through a half-size
// part buffer: waves 0-3 write -> reduce p0+p1+p2+p3 -> waves 4-7 write ->
// += p4..p7. Summation order identical to the old q-ascending loop.
// LDS: lut 128 + part[4][64][33] 33792 + xs[64][68] 17408 = 51328 B.
// ---------------------------------------------------------------------------
__global__ __launch_bounds__(512) void k_depth(
    const unsigned short* __restrict__ hPin,
    const unsigned* __restrict__ mP,
    const float* __restrict__ hin, float* __restrict__ hout,
    const float* __restrict__ invdeg, const float* __restrict__ deg,
    const float* __restrict__ Wc, const float* __restrict__ bc,
    const float* __restrict__ bihf, const float* __restrict__ bhhf,
    const float* __restrict__ Whhf,
    unsigned short* __restrict__ hPout, float* __restrict__ out0, int last)
{
    __shared__ uint2 lut[16];
    __shared__ float part[4][64][33];
    __shared__ float xs[64][68];
    const int t = threadIdx.x, blk = blockIdx.x;   // 128 blocks
    if (t < 16){
        unsigned lo = ((t & 1) ? 0x3F80u : 0u) | ((t & 2) ? 0x3F800000u : 0u);
        unsigned hi = ((t & 4) ? 0x3F80u : 0u) | ((t & 8) ? 0x3F800000u : 0u);
        lut[t] = make_uint2(lo, hi);
    }
    __syncthreads();
    const int q = t >> 6, lane = t & 63;
    const int n = lane & 15, quad = lane >> 4;
    {   // ---- phase A: MFMA neighbor partials; wave = one K-eighth,
        //      4 row-tiles (64 atoms) x 2 column-halves ----
        const int rt0 = blk*4;
        f32x4 acc[4][2];
        #pragma unroll
        for (int r = 0; r < 4; ++r){
            acc[r][0] = (f32x4){0.f,0.f,0.f,0.f};
            acc[r][1] = (f32x4){0.f,0.f,0.f,0.f};
        }
        const unsigned* mb_ = mP + (size_t)rt0*4096 + n;
        #pragma unroll 4
        for (int kk = 0; kk < 32; ++kk){
            const int g = q*32 + kk;
            union { uint4 u; bf16x8 v; } b0, b1;
            b0.u = *(const uint4*)&hPin[(size_t)((g*2+0)*64 + lane)*8];
            b1.u = *(const uint4*)&hPin[(size_t)((g*2+1)*64 + lane)*8];
            #pragma unroll
            for (int rt = 0; rt < 4; ++rt){
                unsigned by = (mb_[(size_t)rt*4096 + g*16] >> (quad*8)) & 0xFFu;
                union { uint2 dd[2]; bf16x8 v; } afx;
                afx.dd[0] = lut[by & 15u];
                afx.dd[1] = lut[by >> 4];
                acc[rt][0] = __builtin_amdgcn_mfma_f32_16x16x32_bf16(afx.v, b0.v, acc[rt][0], 0, 0, 0);
                acc[rt][1] = __builtin_amdgcn_mfma_f32_16x16x32_bf16(afx.v, b1.v, acc[rt][1], 0, 0, 0);
            }
        }
        // two-shift partial staging + reduce (order == old q-ascending)
        if (q < 4){
            #pragma unroll
            for (int rt = 0; rt < 4; ++rt)
                #pragma unroll
                for (int r = 0; r < 4; ++r){
                    int rl = rt*16 + quad*4 + r;
                    part[q][rl][n]      = acc[rt][0][r];
                    part[q][rl][16+n]   = acc[rt][1][r];
                }
        }
        __syncthreads();
        float s[4];
        #pragma unroll
        for (int k = 0; k < 4; ++k){
            int i = k*512 + t;
            int a2 = i >> 5, e = i & 31;
            s[k] = part[0][a2][e] + part[1][a2][e] + part[2][a2][e] + part[3][a2][e];
            xs[a2][e] = hin[(size_t)blk*2048 + i];     // self h staging
        }
        __syncthreads();
        if (q >= 4){
            #pragma unroll
            for (int rt = 0; rt < 4; ++rt)
                #pragma unroll
                for (int r = 0; r < 4; ++r){
                    int rl = rt*16 + quad*4 + r;
                    part[q-4][rl][n]    = acc[rt][0][r];
                    part[q-4][rl][16+n] = acc[rt][1][r];
                }
        }
        __syncthreads();
        #pragma unroll
        for (int k = 0; k < 4; ++k){
            int i = k*512 + t;
            int a2 = i >> 5, e = i & 31;
            s[k] += part[0][a2][e] + part[1][a2][e] + part[2][a2][e] + part[3][a2][e];
            xs[a2][32+e] = s[k];
        }
    }
    __syncthreads();
    {   // ---- phase B: GRU (64 atoms x 8 groups x 4 outputs; body exact) ----
        const int al = t & 63;                 // atom-local 0..63
        const int p  = t >> 6;                 // output group 0..7 (wave-uniform)
        const int atom = blk*64 + al;
        const float idg = invdeg[atom];
        const bool nz = deg[atom] > 0.f;
        float x[64];
        #pragma unroll
        for (int r = 0; r < 16; ++r){
            float4 v = *(const float4*)&xs[al][r*4];
            x[r*4+0]=v.x; x[r*4+1]=v.y; x[r*4+2]=v.z; x[r*4+3]=v.w;
        }
        #pragma unroll
        for (int e = 32; e < 64; ++e) x[e] *= idg;
        const int gg = atom >> 5, qd = (atom >> 3) & 3, j8 = atom & 7;
        #pragma unroll
        for (int jj = 0; jj < 4; ++jj){
            const int j = p*4 + jj;
            const float* wr = Wc + j*64;
            const float* wz = Wc + (32+j)*64;
            const float* wn = Wc + (64+j)*64;
            float gr=0.f, gz=0.f, gn=0.f;
            #pragma unroll
            for (int e = 0; e < 64; ++e){ gr += wr[e]*x[e]; gz += wz[e]*x[e]; gn += wn[e]*x[e]; }
            if (nz){ gr += bc[j]; gz += bc[32+j]; gn += bc[64+j]; }
            else   { gr  = bihf[j]; gz = bihf[32+j]; gn = bihf[64+j]; }
            const float* vr = Whhf + j*32;
            const float* vz = Whhf + (32+j)*32;
            const float* vn = Whhf + (64+j)*32;
            float hr=bhhf[j], hz=bhhf[32+j], hn=bhhf[64+j];
            #pragma unroll
            for (int e = 0; e < 32; ++e){ hr += vr[e]*x[e]; hz += vz[e]*x[e]; hn += vn[e]*x[e]; }
            float rg = 1.f/(1.f + expf(-(gr+hr)));
            float zg = 1.f/(1.f + expf(-(gz+hz)));
            float ng = tanhf(gn + rg*hn);
            float hnew = (1.f - zg)*ng + zg*x[j];
            hout[(size_t)atom*EMBED + j] = hnew;
            hPout[(size_t)((gg*2 + (j>>4))*64 + qd*16 + (j&15))*8 + j8] = f2bf(hnew);
            if (last) out0[(size_t)atom*EMBED + j] = hnew;
        }
    }
}

// ---------------------------------------------------------------------------
__global__ __launch_bounds__(256) void k_pool(
    const float* __restrict__ h, const int* __restrict__ batch,
    const float* __restrict__ poolW, const float* __restrict__ poolb,
    float* __restrict__ out2)
{
    const int b = blockIdx.x, t = threadIdx.x;
    int lo, hi;
    { int l = 0, r = N_ATOMS; while (l < r){ int m = (l+r)>>1; if (batch[m] < b)   l = m+1; else r = m; } lo = l; }
    { int l = 0, r = N_ATOMS; while (l < r){ int m = (l+r)>>1; if (batch[m] < b+1) l = m+1; else r = m; } hi = l; }
    const int cnt = hi - lo;
    __shared__ float ps[8][32];
    __shared__ float mean[32];
    const int e = t & 31, g = t >> 5;
    float acc = 0.f;
    for (int a = lo + g; a < hi; a += 8) acc += h[(size_t)a*EMBED + e];
    ps[g][e] = acc; __syncthreads();
    if (t < 32){
        float s = 0.f;
        #pragma unroll
        for (int gg = 0; gg < 8; ++gg) s += ps[gg][t];
        mean[t] = (cnt > 0) ? s / (float)cnt : 0.f;
    }
    __syncthreads();
    float emb = poolb[t];
    #pragma unroll
    for (int ee = 0; ee < 32; ++ee) emb += mean[ee] * poolW[t*32 + ee];
    out2[b*256 + t] = emb;
}

// ---------------------------------------------------------------------------
extern "C" void kernel_launch(void* const* d_in, const int* in_sizes, int n_in,
                              void* d_out, int out_size, void* d_ws, size_t ws_size,
                              hipStream_t stream)
{
    (void)in_sizes; (void)n_in; (void)out_size;
    const int* af   = (const int*)d_in[0];
    const int* bfe  = (const int*)d_in[1];
    const int* A    = (const int*)d_in[2];
    const int* bidx = (const int*)d_in[3];
    const float* atom_emb = (const float*)d_in[4];
    const float* bond_emb = (const float*)d_in[5];
    const float* msgW  = (const float*)d_in[6];
    const float* msgb  = (const float*)d_in[7];
    const float* Wih   = (const float*)d_in[8];
    const float* Whh   = (const float*)d_in[9];
    const float* bih   = (const float*)d_in[10];
    const float* bhh   = (const float*)d_in[11];
    const float* poolW = (const float*)d_in[12];
    const float* poolb = (const float*)d_in[13];

    // outputs are FLOAT32: h [8192*32] | bond [16384*32] | graph [256*256]
    float* out0 = (float*)d_out;
    float* out1 = out0 + 262144;
    float* out2 = out1 + 524288;

    // deg/invdeg in out2 region (k_pool overwrites last) — proven pattern
    float* deg    = out2;
    float* invdeg = out2 + 8192;

    unsigned*       mP;
    float*          hA; float* hB; float* Wc; float* bc;
    unsigned short* hP0; unsigned short* hP1;
    const int wsok = (ws_size >= (size_t)33554432) ? 1 : 0;
    if (wsok){
        char* W = (char*)d_ws;
        mP      = (unsigned*)(W + 8388608);           // 8 MiB packed
        hP0     = (unsigned short*)(W + 16777216);    // 512 KiB
        hA      = (float*)(W + 17825792);             // 1 MiB
        hB      = (float*)(W + 18874368);             // 1 MiB
        Wc      = (float*)(W + 19922944);             // 240 KiB
        bc      = (float*)(W + 20185088);
        hP1     = (unsigned short*)(W + 20971520);    // 512 KiB
        // ONE dispatch: setup first (runs under the HBM-bound A-scan)
        k_pre2<<<dim3(11508), dim3(256), 0, stream>>>(A, mP, deg, invdeg,
            af, atom_emb, msgW, msgb, Wih, bih, hA, hP0, Wc, bc,
            bfe, bond_emb, out1);
    } else {
        // A-buffer scratch fallback, R10-proven ordering (unchanged from R2).
        unsigned long long* maskRM;
        char* Ab = (char*)d_in[2];
        hA      = (float*)(Ab + 0);
        hB      = (float*)(Ab + 1048576);
        hP0     = (unsigned short*)(Ab + 2097152);
        Wc      = (float*)(Ab + 2621440);
        bc      = (float*)(Ab + 2867200);
        hP1     = (unsigned short*)(Ab + 4194304);
        mP      = (unsigned*)(Ab + 13631488);         // 8 MiB, ends 21.6 MiB
        maskRM  = (unsigned long long*)(Ab + 260046848);
        k_preA<<<dim3(1),    dim3(256), 0, stream>>>(A, maskRM, 8191);
        k_preA<<<dim3(7),    dim3(256), 0, stream>>>(A, maskRM, 8184);
        k_preA<<<dim3(248),  dim3(256), 0, stream>>>(A, maskRM, 7936);
        k_preA<<<dim3(7936), dim3(256), 0, stream>>>(A, maskRM, 0);
        k_prep<<<dim3(3828), dim3(256), 0, stream>>>((const unsigned*)maskRM, mP,
            deg, invdeg, af, atom_emb, msgW, msgb, Wih, bih, hA, hP0, Wc, bc,
            bfe, bond_emb, out1);
    }

    float* hin = hA; float* hout = hB;
    unsigned short* hPi = hP0; unsigned short* hPo = hP1;
    for (int d = 0; d < DEPTHN; ++d){
        k_depth<<<dim3(128), dim3(512), 0, stream>>>(hPi, mP, hin, hout,
            invdeg, deg, Wc + d*6144, bc + d*96, bih + d*96, bhh + d*96,
            Whh + d*3072, hPo, out0, (d == DEPTHN-1) ? 1 : 0);
        float* tf = hin; hin = hout; hout = tf;
        unsigned short* tp = hPi; hPi = hPo; hPo = tp;
    }
    k_pool<<<dim3(256), dim3(256), 0, stream>>>(hin, bidx, poolW, poolb, out2);
}

// Round 6
// 665.530 us; speedup vs baseline: 1.2029x; 1.2029x over previous
//
#include <hip/hip_runtime.h>
#include <stdint.h>

#define N_ATOMS 8192
#define EMBED   32
#define DEPTHN  10

typedef short bf16x8 __attribute__((ext_vector_type(8)));
typedef float f32x4  __attribute__((ext_vector_type(4)));

__device__ __forceinline__ unsigned short f2bf(float f){
    unsigned u = __builtin_bit_cast(unsigned, f);
    u = u + 0x7FFFu + ((u >> 16) & 1u);
    return (unsigned short)(u >> 16);
}

// ---------------------------------------------------------------------------
// k_preA (fallback path only; R10-proven form): one row per block. Row-major
// mask64 writes, LDS staged. u32 word g of row i covers cols 32g..32g+31.
// ---------------------------------------------------------------------------
__global__ __launch_bounds__(256) void k_preA(const int* __restrict__ A,
                                              unsigned long long* __restrict__ mask,
                                              int row0)
{
    const int i = row0 + blockIdx.x;
    const int t = threadIdx.x, w = t >> 6, l = t & 63;
    const int* row = A + (size_t)i * N_ATOMS;
    __shared__ unsigned long long lm[128];
    #pragma unroll
    for (int k = 0; k < 32; ++k){
        int j = k*256 + t;
        unsigned long long m = __ballot(row[j] != 0);
        if (l == 0) lm[k*4 + w] = m;
    }
    __syncthreads();
    if (t < 128) mask[(size_t)i*128 + t] = lm[t];
}

// ---------------------------------------------------------------------------
// k_pre2 (wsok path): ONE dispatch = preA-direct + setup. R4-proven order:
//  blocks 0..8191   : mask row -> mP DIRECTLY (packed MFMA order, no maskRM,
//                     no separate pack pass) + deg/invdeg via popc.
//                     Row swizzle i = ((blk>>7)*8+(blk&7))*16 + ((blk>>3)&15):
//                     the 16 writers of each 128-B mP line share one XCD
//                     (blk%8 heuristic) and a 128-block dispatch window ->
//                     full-line L2 write combining. A-read locality kept
//                     (permutation is within 4 MiB spans). Perf-only heuristic.
//  blocks 8192+     : h0 gather, Wc/bc precompute, bond gather (old setup).
// (R5 lesson: setup-FIRST ordering regressed; keep preA-first.)
// ---------------------------------------------------------------------------
__global__ __launch_bounds__(256) void k_pre2(
    const int* __restrict__ A, unsigned* __restrict__ mP,
    float* __restrict__ deg, float* __restrict__ invdeg,
    const int* __restrict__ af, const float* __restrict__ atom_emb,
    const float* __restrict__ msgW, const float* __restrict__ msgb,
    const float* __restrict__ Wih, const float* __restrict__ bih,
    float* __restrict__ hA, unsigned short* __restrict__ hP,
    float* __restrict__ Wc, float* __restrict__ bc,
    const int* __restrict__ bfeat, const float* __restrict__ bondf,
    float* __restrict__ out1)
{
    const int t = threadIdx.x;
    __shared__ unsigned lm[256];
    __shared__ int red[4];
    if (blockIdx.x < 8192){
        const int blk = blockIdx.x;
        const int grp = (blk >> 7)*8 + (blk & 7);
        const int n   = (blk >> 3) & 15;
        const int i   = grp*16 + n;
        const int w = t >> 6, l = t & 63;
        const int* row = A + (size_t)i * N_ATOMS;
        #pragma unroll
        for (int k = 0; k < 32; ++k){
            int j = k*256 + t;
            unsigned long long m = __ballot(row[j] != 0);
            if (l == 0){
                lm[(k*4 + w)*2]     = (unsigned)m;
                lm[(k*4 + w)*2 + 1] = (unsigned)(m >> 32);
            }
        }
        __syncthreads();
        // degree: integer popc over the 256 u32 words (order-free, exact)
        int cnt = __popc(lm[t]);
        #pragma unroll
        for (int off = 32; off >= 1; off >>= 1) cnt += __shfl_down(cnt, off, 64);
        if (l == 0) red[w] = cnt;
        __syncthreads();
        if (t == 0){
            int s = red[0] + red[1] + red[2] + red[3];
            deg[i] = (float)s;
            invdeg[i] = 1.f / fmaxf((float)s, 1.f);
        }
        // direct packed-order scatter: mP[grp*4096 + g*16 + n] = rowword g
        mP[(size_t)grp*4096 + t*16 + n] = lm[t];
    } else {
        const int blk = blockIdx.x - 8192;
        if (blk < 1024){                       // h0: 8192*32
            int idx = blk*256 + t;
            int i = idx >> 5, e = idx & 31;
            float v = atom_emb[af[i]*EMBED + e];
            hA[idx] = v;
            int g = i >> 5, qd = (i >> 3) & 3, j8 = i & 7;
            hP[(size_t)((g*2 + (e>>4))*64 + qd*16 + (e&15))*8 + j8] = f2bf(v);
        } else if (blk < 1264){                // Wc: 10*96*64, K=256
            int o = (blk-1024)*256 + t;
            int d = o / 6144, r = o % 6144, g = r >> 6, e = r & 63;
            const float* wi = Wih  + (size_t)(d*96 + g)*256;
            const float* mw = msgW + (size_t)d*256*64 + e;
            float acc = 0.f;
            for (int hh = 0; hh < 256; ++hh) acc += wi[hh] * mw[hh*64];
            Wc[o] = acc;
        } else if (blk < 1268){                // bc: 10*96
            int o = (blk-1264)*256 + t;
            if (o < 960){
                int d = o / 96;
                const float* wi = Wih + (size_t)o*256;   // o = d*96+g
                const float* mb = msgb + d*256;
                float acc = 0.f;
                for (int hh = 0; hh < 256; ++hh) acc += wi[hh] * mb[hh];
                bc[o] = acc + bih[o];
            }
        } else {                               // bond embeddings: 16384*32
            int idx = (blk-1268)*256 + t;
            out1[idx] = bondf[bfeat[idx >> 5]*EMBED + (idx & 31)];
        }
    }
}

// ---------------------------------------------------------------------------
// k_prep (fallback path only): FUSED k_pack + k_setup, exactly as R2.
// ---------------------------------------------------------------------------
__global__ __launch_bounds__(256) void k_prep(
    const unsigned* __restrict__ maskRM, unsigned* __restrict__ mP,
    float* __restrict__ deg, float* __restrict__ invdeg,
    const int* __restrict__ af, const float* __restrict__ atom_emb,
    const float* __restrict__ msgW, const float* __restrict__ msgb,
    const float* __restrict__ Wih, const float* __restrict__ bih,
    float* __restrict__ hA, unsigned short* __restrict__ hP,
    float* __restrict__ Wc, float* __restrict__ bc,
    const int* __restrict__ bfeat, const float* __restrict__ bondf,
    float* __restrict__ out1)
{
    const int t = threadIdx.x;
    if (blockIdx.x < 512){
        const int grp = blockIdx.x;
        __shared__ unsigned lm[16*260];
        __shared__ int red[256];
        #pragma unroll
        for (int s = 0; s < 16; ++s)
            lm[s*260 + t] = maskRM[(size_t)grp*4096 + s*256 + t];
        __syncthreads();
        {
            int r = t >> 4, seg = t & 15, cnt = 0;
            #pragma unroll
            for (int k = 0; k < 16; ++k) cnt += __popc(lm[r*260 + seg*16 + k]);
            red[t] = cnt; __syncthreads();
            if (t < 16){
                int s = 0;
                #pragma unroll
                for (int k = 0; k < 16; ++k) s += red[t*16 + k];
                deg[grp*16 + t] = (float)s;
                invdeg[grp*16 + t] = 1.f / fmaxf((float)s, 1.f);
            }
        }
        unsigned* out = mP + (size_t)grp*4096;
        #pragma unroll
        for (int s = 0; s < 16; ++s){
            int W = s*256 + t;
            out[W] = lm[(W & 15)*260 + (W >> 4)];
        }
    } else {
        const int blk = blockIdx.x - 512;
        if (blk < 1024){                       // h0: 8192*32
            int idx = blk*256 + t;
            int i = idx >> 5, e = idx & 31;
            float v = atom_emb[af[i]*EMBED + e];
            hA[idx] = v;
            int g = i >> 5, qd = (i >> 3) & 3, j8 = i & 7;
            hP[(size_t)((g*2 + (e>>4))*64 + qd*16 + (e&15))*8 + j8] = f2bf(v);
        } else if (blk < 1264){                // Wc
            int o = (blk-1024)*256 + t;
            int d = o / 6144, r = o % 6144, g = r >> 6, e = r & 63;
            const float* wi = Wih  + (size_t)(d*96 + g)*256;
            const float* mw = msgW + (size_t)d*256*64 + e;
            float acc = 0.f;
            for (int hh = 0; hh < 256; ++hh) acc += wi[hh] * mw[hh*64];
            Wc[o] = acc;
        } else if (blk < 1268){                // bc
            int o = (blk-1264)*256 + t;
            if (o < 960){
                int d = o / 96;
                const float* wi = Wih + (size_t)o*256;
                const float* mb = msgb + d*256;
                float acc = 0.f;
                for (int hh = 0; hh < 256; ++hh) acc += wi[hh] * mb[hh];
                bc[o] = acc + bih[o];
            }
        } else {                               // bond embeddings
            int idx = (blk-1268)*256 + t;
            out1[idx] = bondf[bfeat[idx >> 5]*EMBED + (idx & 31)];
        }
    }
}

// ---------------------------------------------------------------------------
// k_depth: FUSED k_nei + k_gru, one dispatch per depth (R2/R4-proven form,
// 256 blocks x 512 thr — R5's 128x64 variant regressed, do not repeat).
// Phase A: 8 waves = 8 K-eighths (nibble-LUT expansion), partials -> LDS.
// Reduce q ascending. Phase B: GRU. hP double-buffered across dispatches.
// ---------------------------------------------------------------------------
__global__ __launch_bounds__(512) void k_depth(
    const unsigned short* __restrict__ hPin,
    const unsigned* __restrict__ mP,
    const float* __restrict__ hin, float* __restrict__ hout,
    const float* __restrict__ invdeg, const float* __restrict__ deg,
    const float* __restrict__ Wc, const float* __restrict__ bc,
    const float* __restrict__ bihf, const float* __restrict__ bhhf,
    const float* __restrict__ Whhf,
    unsigned short* __restrict__ hPout, float* __restrict__ out0, int last)
{
    __shared__ uint2 lut[16];
    __shared__ float part[8][32][33];
    __shared__ float xs[32][68];
    const int t = threadIdx.x, blk = blockIdx.x;
    if (t < 16){
        unsigned lo = ((t & 1) ? 0x3F80u : 0u) | ((t & 2) ? 0x3F800000u : 0u);
        unsigned hi = ((t & 4) ? 0x3F80u : 0u) | ((t & 8) ? 0x3F800000u : 0u);
        lut[t] = make_uint2(lo, hi);
    }
    __syncthreads();
    {   // ---- phase A: MFMA neighbor partial sums, wave = one K-eighth ----
        const int q = t >> 6, lane = t & 63;
        const int n = lane & 15, quad = lane >> 4;
        const int rt0 = blk*2;
        f32x4 a00 = {0.f,0.f,0.f,0.f};
        f32x4 a01 = {0.f,0.f,0.f,0.f};
        f32x4 a10 = {0.f,0.f,0.f,0.f};
        f32x4 a11 = {0.f,0.f,0.f,0.f};
        const unsigned* m0 = mP + (size_t)rt0*4096 + n;
        const unsigned* m1 = m0 + 4096;
        #pragma unroll 4
        for (int kk = 0; kk < 32; ++kk){
            const int g = q*32 + kk;
            union { uint4 u; bf16x8 v; } b0, b1;
            b0.u = *(const uint4*)&hPin[(size_t)((g*2+0)*64 + lane)*8];
            b1.u = *(const uint4*)&hPin[(size_t)((g*2+1)*64 + lane)*8];
            unsigned by0 = (m0[g*16] >> (quad*8)) & 0xFFu;
            unsigned by1 = (m1[g*16] >> (quad*8)) & 0xFFu;
            union { uint2 dd[2]; bf16x8 v; } af0, af1;
            af0.dd[0] = lut[by0 & 15u];
            af0.dd[1] = lut[by0 >> 4];
            af1.dd[0] = lut[by1 & 15u];
            af1.dd[1] = lut[by1 >> 4];
            a00 = __builtin_amdgcn_mfma_f32_16x16x32_bf16(af0.v, b0.v, a00, 0, 0, 0);
            a01 = __builtin_amdgcn_mfma_f32_16x16x32_bf16(af0.v, b1.v, a01, 0, 0, 0);
            a10 = __builtin_amdgcn_mfma_f32_16x16x32_bf16(af1.v, b0.v, a10, 0, 0, 0);
            a11 = __builtin_amdgcn_mfma_f32_16x16x32_bf16(af1.v, b1.v, a11, 0, 0, 0);
        }
        #pragma unroll
        for (int r = 0; r < 4; ++r){
            int rl = quad*4 + r;
            part[q][rl][n]       = a00[r];
            part[q][rl][16+n]    = a01[r];
            part[q][16+rl][n]    = a10[r];
            part[q][16+rl][16+n] = a11[r];
        }
    }
    __syncthreads();
    {   // ---- reduce partials (q ascending == proven order) + stage ----
        #pragma unroll
        for (int ii = 0; ii < 2; ++ii){
            int i = ii*512 + t;
            int a = i >> 5, e = i & 31;
            float s = 0.f;
            #pragma unroll
            for (int q = 0; q < 8; ++q) s += part[q][a][e];
            xs[a][32+e] = s;
            xs[a][e] = hin[(size_t)blk*1024 + i];
        }
    }
    __syncthreads();
    {   // ---- phase B: GRU ----
        const int a = t & 15, pw = t >> 4;
        const int al = a + (pw & 16);
        const int p  = pw & 15;
        const int atom = blk*32 + al;
        const float idg = invdeg[atom];
        const bool nz = deg[atom] > 0.f;
        float x[64];
        #pragma unroll
        for (int r = 0; r < 16; ++r){
            float4 v = *(const float4*)&xs[al][r*4];
            x[r*4+0]=v.x; x[r*4+1]=v.y; x[r*4+2]=v.z; x[r*4+3]=v.w;
        }
        #pragma unroll
        for (int e = 32; e < 64; ++e) x[e] *= idg;
        const int gg = atom >> 5, qd = (atom >> 3) & 3, j8 = atom & 7;
        #pragma unroll
        for (int jj = 0; jj < 2; ++jj){
            const int j = p*2 + jj;
            const float* wr = Wc + j*64;
            const float* wz = Wc + (32+j)*64;
            const float* wn = Wc + (64+j)*64;
            float gr=0.f, gz=0.f, gn=0.f;
            #pragma unroll
            for (int e = 0; e < 64; ++e){ gr += wr[e]*x[e]; gz += wz[e]*x[e]; gn += wn[e]*x[e]; }
            if (nz){ gr += bc[j]; gz += bc[32+j]; gn += bc[64+j]; }
            else   { gr  = bihf[j]; gz = bihf[32+j]; gn = bihf[64+j]; }
            const float* vr = Whhf + j*32;
            const float* vz = Whhf + (32+j)*32;
            const float* vn = Whhf + (64+j)*32;
            float hr=bhhf[j], hz=bhhf[32+j], hn=bhhf[64+j];
            #pragma unroll
            for (int e = 0; e < 32; ++e){ hr += vr[e]*x[e]; hz += vz[e]*x[e]; hn += vn[e]*x[e]; }
            float rg = 1.f/(1.f + expf(-(gr+hr)));
            float zg = 1.f/(1.f + expf(-(gz+hz)));
            float ng = tanhf(gn + rg*hn);
            float hnew = (1.f - zg)*ng + zg*x[j];
            hout[(size_t)atom*EMBED + j] = hnew;
            hPout[(size_t)((gg*2 + (j>>4))*64 + qd*16 + (j&15))*8 + j8] = f2bf(hnew);
            if (last) out0[(size_t)atom*EMBED + j] = hnew;
        }
    }
}

// ---------------------------------------------------------------------------
__global__ __launch_bounds__(256) void k_pool(
    const float* __restrict__ h, const int* __restrict__ batch,
    const float* __restrict__ poolW, const float* __restrict__ poolb,
    float* __restrict__ out2)
{
    const int b = blockIdx.x, t = threadIdx.x;
    int lo, hi;
    { int l = 0, r = N_ATOMS; while (l < r){ int m = (l+r)>>1; if (batch[m] < b)   l = m+1; else r = m; } lo = l; }
    { int l = 0, r = N_ATOMS; while (l < r){ int m = (l+r)>>1; if (batch[m] < b+1) l = m+1; else r = m; } hi = l; }
    const int cnt = hi - lo;
    __shared__ float ps[8][32];
    __shared__ float mean[32];
    const int e = t & 31, g = t >> 5;
    float acc = 0.f;
    for (int a = lo + g; a < hi; a += 8) acc += h[(size_t)a*EMBED + e];
    ps[g][e] = acc; __syncthreads();
    if (t < 32){
        float s = 0.f;
        #pragma unroll
        for (int gg = 0; gg < 8; ++gg) s += ps[gg][t];
        mean[t] = (cnt > 0) ? s / (float)cnt : 0.f;
    }
    __syncthreads();
    float emb = poolb[t];
    #pragma unroll
    for (int ee = 0; ee < 32; ++ee) emb += mean[ee] * poolW[t*32 + ee];
    out2[b*256 + t] = emb;
}

// ---------------------------------------------------------------------------
extern "C" void kernel_launch(void* const* d_in, const int* in_sizes, int n_in,
                              void* d_out, int out_size, void* d_ws, size_t ws_size,
                              hipStream_t stream)
{
    (void)in_sizes; (void)n_in; (void)out_size;
    const int* af   = (const int*)d_in[0];
    const int* bfe  = (const int*)d_in[1];
    const int* A    = (const int*)d_in[2];
    const int* bidx = (const int*)d_in[3];
    const float* atom_emb = (const float*)d_in[4];
    const float* bond_emb = (const float*)d_in[5];
    const float* msgW  = (const float*)d_in[6];
    const float* msgb  = (const float*)d_in[7];
    const float* Wih   = (const float*)d_in[8];
    const float* Whh   = (const float*)d_in[9];
    const float* bih   = (const float*)d_in[10];
    const float* bhh   = (const float*)d_in[11];
    const float* poolW = (const float*)d_in[12];
    const float* poolb = (const float*)d_in[13];

    // outputs are FLOAT32: h [8192*32] | bond [16384*32] | graph [256*256]
    float* out0 = (float*)d_out;
    float* out1 = out0 + 262144;
    float* out2 = out1 + 524288;

    // deg/invdeg in out2 region (k_pool overwrites last) — proven pattern
    float* deg    = out2;
    float* invdeg = out2 + 8192;

    unsigned*       mP;
    float*          hA; float* hB; float* Wc; float* bc;
    unsigned short* hP0; unsigned short* hP1;
    const int wsok = (ws_size >= (size_t)33554432) ? 1 : 0;
    if (wsok){
        char* W = (char*)d_ws;
        mP      = (unsigned*)(W + 8388608);           // 8 MiB packed
        hP0     = (unsigned short*)(W + 16777216);    // 512 KiB
        hA      = (float*)(W + 17825792);             // 1 MiB
        hB      = (float*)(W + 18874368);             // 1 MiB
        Wc      = (float*)(W + 19922944);             // 240 KiB
        bc      = (float*)(W + 20185088);
        hP1     = (unsigned short*)(W + 20971520);    // 512 KiB
        // ONE dispatch: preA-direct-to-mP (+deg) and setup in its shadow
        k_pre2<<<dim3(11508), dim3(256), 0, stream>>>(A, mP, deg, invdeg,
            af, atom_emb, msgW, msgb, Wih, bih, hA, hP0, Wc, bc,
            bfe, bond_emb, out1);
    } else {
        // A-buffer scratch fallback, R10-proven ordering (unchanged from R2).
        unsigned long long* maskRM;
        char* Ab = (char*)d_in[2];
        hA      = (float*)(Ab + 0);
        hB      = (float*)(Ab + 1048576);
        hP0     = (unsigned short*)(Ab + 2097152);
        Wc      = (float*)(Ab + 2621440);
        bc      = (float*)(Ab + 2867200);
        hP1     = (unsigned short*)(Ab + 4194304);
        mP      = (unsigned*)(Ab + 13631488);         // 8 MiB, ends 21.6 MiB
        maskRM  = (unsigned long long*)(Ab + 260046848);
        k_preA<<<dim3(1),    dim3(256), 0, stream>>>(A, maskRM, 8191);
        k_preA<<<dim3(7),    dim3(256), 0, stream>>>(A, maskRM, 8184);
        k_preA<<<dim3(248),  dim3(256), 0, stream>>>(A, maskRM, 7936);
        k_preA<<<dim3(7936), dim3(256), 0, stream>>>(A, maskRM, 0);
        k_prep<<<dim3(3828), dim3(256), 0, stream>>>((const unsigned*)maskRM, mP,
            deg, invdeg, af, atom_emb, msgW, msgb, Wih, bih, hA, hP0, Wc, bc,
            bfe, bond_emb, out1);
    }

    float* hin = hA; float* hout = hB;
    unsigned short* hPi = hP0; unsigned short* hPo = hP1;
    for (int d = 0; d < DEPTHN; ++d){
        k_depth<<<dim3(256), dim3(512), 0, stream>>>(hPi, mP, hin, hout,
            invdeg, deg, Wc + d*6144, bc + d*96, bih + d*96, bhh + d*96,
            Whh + d*3072, hPo, out0, (d == DEPTHN-1) ? 1 : 0);
        float* tf = hin; hin = hout; hout = tf;
        unsigned short* tp = hPi; hPi = hPo; hPo = tp;
    }
    k_pool<<<dim3(256), dim3(256), 0, stream>>>(hin, bidx, poolW, poolb, out2);
}